// Round 2
// 256.122 us; speedup vs baseline: 1.0063x; 1.0063x over previous
//
#include <hip/hip_runtime.h>
#include <stdint.h>

// LeadLagSignature: depth-3 signature of lead-lag path over sliding 16-patches.
// Increments alternate (Delta,0)/(0,Delta) -> half-sparse Chen updates.
// One wave per position; lane owns b=L&15, a in {h,h+4,h+8,h+12}, h=L>>4.
// Input: float32 [8192,8]. Output: float32, concat [8192,16][8192,256][8192,4096].
// Epilogue: region-3 (S3) staged through LDS (pad stride 20 floats -> conflict-free
// b128 both phases) so every global store instruction is 1KB contiguous.
// R1: all output stores are NON-TEMPORAL (nt) — output is write-once, never
// re-read; nt skips L2 allocate, killing the RFO fetch (~83 MB) and the
// dirty-line churn that inflated WRITE_SIZE to ~4.6x logical bytes.
// R2: nt builtin needs a NATIVE vector type (ext_vector_type), not HIP float4.

#define SEQ   8192
#define IND   8
#define NM    15     // number of Delta rows per patch
#define WAVES 4

typedef float f32x4 __attribute__((ext_vector_type(4)));

__global__ __launch_bounds__(WAVES * 64, 4)
void LeadLagSignature_48361331753748_kernel(const float* __restrict__ x,
                                            float* __restrict__ out)
{
    __shared__ float dlds[WAVES][NM * 8];
    __shared__ float stage[WAVES][64 * 20];   // 5 KB per wave, reused across r
    const int tid = threadIdx.x;
    const int wv  = tid >> 6;
    const int L   = tid & 63;
    const int i   = blockIdx.x * WAVES + wv;   // output position
    const int h   = L >> 4;
    const int b   = L & 15;
    const int bm  = b & 7;
    const float maskLo = (b < 8) ? 1.0f : 0.0f;
    const float maskHi = 1.0f - maskLo;

    // Stage Deltas: Delta_m[c] = patch[m+1][c] - patch[m][c], patch[p] = xp[i+p]
    // (xp = 15 zero rows then x). 120 values; lanes cover idx and idx+64.
    float* dbuf = dlds[wv];
    #pragma unroll
    for (int q = 0; q < 2; ++q) {
        int idx = L + q * 64;
        if (idx < NM * 8) {
            int m = idx >> 3, c = idx & 7;
            int r1 = i + m - 14;   // row of patch[m+1]
            int r0 = i + m - 15;   // row of patch[m]
            float v1 = (r1 >= 0) ? x[r1 * IND + c] : 0.0f;
            float v0 = (r0 >= 0) ? x[r0 * IND + c] : 0.0f;
            dbuf[idx] = v1 - v0;
        }
    }
    __syncthreads();

    float s1[4] = {0.f, 0.f, 0.f, 0.f};       // S1[h+4r]
    float s2[4] = {0.f, 0.f, 0.f, 0.f};       // S2[h+4r, b]
    float s3[4][16];                          // S3[h+4r, b, :]
    #pragma unroll
    for (int r = 0; r < 4; ++r)
        #pragma unroll
        for (int c = 0; c < 16; ++c) s3[r][c] = 0.f;

    const float SIXTH = 0.16666666666666666f;

    for (int m = 0; m < NM; ++m) {
        const float* dm = dbuf + m * 8;
        const float4 lo = *(const float4*)(dm);      // broadcast, 16B aligned
        const float4 hi = *(const float4*)(dm + 4);
        const float dh  = dm[h];        // Delta[h]   = w[a] for rows h / h+8
        const float dh4 = dm[h + 4];    // Delta[h+4] = w[a] for rows h+4 / h+12
        const float dbr = dm[bm];       // Delta[b mod 8]
        const float d[8] = {lo.x, lo.y, lo.z, lo.w, hi.x, hi.y, hi.z, hi.w};

        // ---- u-step: w = (Delta, 0); active c = 0..7; w[a]!=0 for r=0,1 ----
        {
            const float wb = dbr * maskLo;             // w[b]
            float t0 = fmaf(SIXTH, dh,  0.5f * s1[0]);
            float t1 = fmaf(SIXTH, dh4, 0.5f * s1[1]);
            float c0 = fmaf(wb, t0, s2[0]);
            float c1 = fmaf(wb, t1, s2[1]);
            float c2 = fmaf(wb, 0.5f * s1[2], s2[2]);
            float c3 = fmaf(wb, 0.5f * s1[3], s2[3]);
            #pragma unroll
            for (int c = 0; c < 8; ++c) {
                s3[0][c] = fmaf(c0, d[c], s3[0][c]);
                s3[1][c] = fmaf(c1, d[c], s3[1][c]);
                s3[2][c] = fmaf(c2, d[c], s3[2][c]);
                s3[3][c] = fmaf(c3, d[c], s3[3][c]);
            }
            s2[0] = fmaf(wb, fmaf(0.5f, dh,  s1[0]), s2[0]);
            s2[1] = fmaf(wb, fmaf(0.5f, dh4, s1[1]), s2[1]);
            s2[2] = fmaf(wb, s1[2], s2[2]);
            s2[3] = fmaf(wb, s1[3], s2[3]);
            s1[0] += dh;
            s1[1] += dh4;
        }
        // ---- v-step: w = (0, Delta); active c = 8..15; w[a]!=0 for r=2,3 ----
        {
            const float wb = dbr * maskHi;
            float t2 = fmaf(SIXTH, dh,  0.5f * s1[2]);
            float t3 = fmaf(SIXTH, dh4, 0.5f * s1[3]);
            float c0 = fmaf(wb, 0.5f * s1[0], s2[0]);
            float c1 = fmaf(wb, 0.5f * s1[1], s2[1]);
            float c2 = fmaf(wb, t2, s2[2]);
            float c3 = fmaf(wb, t3, s2[3]);
            #pragma unroll
            for (int c = 0; c < 8; ++c) {
                s3[0][8 + c] = fmaf(c0, d[c], s3[0][8 + c]);
                s3[1][8 + c] = fmaf(c1, d[c], s3[1][8 + c]);
                s3[2][8 + c] = fmaf(c2, d[c], s3[2][8 + c]);
                s3[3][8 + c] = fmaf(c3, d[c], s3[3][8 + c]);
            }
            s2[0] = fmaf(wb, s1[0], s2[0]);
            s2[1] = fmaf(wb, s1[1], s2[1]);
            s2[2] = fmaf(wb, fmaf(0.5f, dh,  s1[2]), s2[2]);
            s2[3] = fmaf(wb, fmaf(0.5f, dh4, s1[3]), s2[3]);
            s1[2] += dh;
            s1[3] += dh4;
        }
    }

    // ---- epilogue. Outputs concatenated: [SEQ,16][SEQ,256][SEQ,4096] ----
    const int o1 = i * 16;
    const int o2 = SEQ * 16 + i * 256;
    const long o3 = (long)SEQ * (16 + 256) + (long)i * 4096;

    // S2: lane-consecutive 4B stores (already full-line coalesced).
    #pragma unroll
    for (int r = 0; r < 4; ++r)
        __builtin_nontemporal_store(s2[r], out + o2 + L + 64 * r);
    if (b == 0) {
        #pragma unroll
        for (int r = 0; r < 4; ++r)
            __builtin_nontemporal_store(s1[r], out + o1 + h + 4 * r);
    }

    // S3: LDS transpose per r-tile -> contiguous 1KB global stores (nt).
    float* st = stage[wv];
    for (int r = 0; r < 4; ++r) {
        // write phase: lane L's 16 floats at padded row L*20 (conflict-free b128)
        float4* wp = (float4*)(st + L * 20);
        wp[0] = make_float4(s3[r][0],  s3[r][1],  s3[r][2],  s3[r][3]);
        wp[1] = make_float4(s3[r][4],  s3[r][5],  s3[r][6],  s3[r][7]);
        wp[2] = make_float4(s3[r][8],  s3[r][9],  s3[r][10], s3[r][11]);
        wp[3] = make_float4(s3[r][12], s3[r][13], s3[r][14], s3[r][15]);
        __syncthreads();
        // read phase: lane L covers global floats tile + 256j + 4L (+0..3)
        #pragma unroll
        for (int j = 0; j < 4; ++j) {
            f32x4 v = *(const f32x4*)(st + (16 * j + (L >> 2)) * 20 + 4 * (L & 3));
            __builtin_nontemporal_store(v, (f32x4*)(out + o3 + 1024 * r + 256 * j + 4 * L));
        }
        __syncthreads();   // protect buffer reuse for next r
    }
}

extern "C" void kernel_launch(void* const* d_in, const int* in_sizes, int n_in,
                              void* d_out, int out_size, void* d_ws, size_t ws_size,
                              hipStream_t stream) {
    (void)in_sizes; (void)n_in; (void)d_ws; (void)ws_size; (void)out_size;
    const float* x = (const float*)d_in[0];
    float* out = (float*)d_out;
    dim3 grid(SEQ / WAVES);
    dim3 block(WAVES * 64);
    hipLaunchKernelGGL(LeadLagSignature_48361331753748_kernel, grid, block, 0, stream,
                       x, out);
}

// Round 3
// 171.226 us; speedup vs baseline: 1.5052x; 1.4958x over previous
//
#include <hip/hip_runtime.h>
#include <stdint.h>

// LeadLagSignature: depth-3 signature of lead-lag path over sliding 16-patches.
// Increments alternate (Delta,0)/(0,Delta) -> half-sparse Chen updates.
// One wave per position; lane owns b=L&15, a in {h,h+4,h+8,h+12}, h=L>>4.
// Input: float32 [8192,8]. Output: float32, concat [8192,16][8192,256][8192,4096].
// R3: waves are fully independent (dlds[wv] is wave-private) -> ALL barriers
// removed; intra-wave LDS visibility via s_waitcnt lgkmcnt(0) (DS pipe is
// in-order within a wave) + sched_barrier to pin compiler ordering.
// S3 epilogue: for fixed r, lane L=(h<<4)|b owns out3 floats r*1024 + L*16 +
// (0..15) -> the wave's 4KB r-tile is contiguous at 64B/lane. Direct CACHED
// stores (L2 merges the 4-instr interleave into full lines); LDS transpose +
// stage buffer deleted (22.5KB -> 2KB LDS/block).
// __launch_bounds__(256,2): allow up to 256 VGPRs so s3[4][16] lives in real
// VGPRs (R2's VGPR_Count=64 forced AGPR/scratch shuffling of the accumulators).

#define SEQ   8192
#define IND   8
#define NM    15     // number of Delta rows per patch
#define WAVES 4

typedef float f32x4 __attribute__((ext_vector_type(4)));

__global__ __launch_bounds__(WAVES * 64, 2)
void LeadLagSignature_48361331753748_kernel(const float* __restrict__ x,
                                            float* __restrict__ out)
{
    __shared__ float dlds[WAVES][NM * 8];
    const int tid = threadIdx.x;
    const int wv  = tid >> 6;
    const int L   = tid & 63;
    const int i   = blockIdx.x * WAVES + wv;   // output position
    const int h   = L >> 4;
    const int b   = L & 15;
    const int bm  = b & 7;
    const float maskLo = (b < 8) ? 1.0f : 0.0f;
    const float maskHi = 1.0f - maskLo;

    // Stage Deltas: Delta_m[c] = patch[m+1][c] - patch[m][c], patch[p] = xp[i+p]
    // (xp = 15 zero rows then x). 120 values; lanes cover idx and idx+64.
    // Wave-private buffer: no __syncthreads needed, only intra-wave DS ordering.
    float* dbuf = dlds[wv];
    #pragma unroll
    for (int q = 0; q < 2; ++q) {
        int idx = L + q * 64;
        if (idx < NM * 8) {
            int m = idx >> 3, c = idx & 7;
            int r1 = i + m - 14;   // row of patch[m+1]
            int r0 = i + m - 15;   // row of patch[m]
            float v1 = (r1 >= 0) ? x[r1 * IND + c] : 0.0f;
            float v0 = (r0 >= 0) ? x[r0 * IND + c] : 0.0f;
            dbuf[idx] = v1 - v0;
        }
    }
    asm volatile("s_waitcnt lgkmcnt(0)" ::: "memory");
    __builtin_amdgcn_sched_barrier(0);

    float s1[4] = {0.f, 0.f, 0.f, 0.f};       // S1[h+4r]
    float s2[4] = {0.f, 0.f, 0.f, 0.f};       // S2[h+4r, b]
    float s3[4][16];                          // S3[h+4r, b, :]
    #pragma unroll
    for (int r = 0; r < 4; ++r)
        #pragma unroll
        for (int c = 0; c < 16; ++c) s3[r][c] = 0.f;

    const float SIXTH = 0.16666666666666666f;

    for (int m = 0; m < NM; ++m) {
        const float* dm = dbuf + m * 8;
        const float4 lo = *(const float4*)(dm);      // broadcast, 16B aligned
        const float4 hi = *(const float4*)(dm + 4);
        const float dh  = dm[h];        // Delta[h]   = w[a] for rows h / h+8
        const float dh4 = dm[h + 4];    // Delta[h+4] = w[a] for rows h+4 / h+12
        const float dbr = dm[bm];       // Delta[b mod 8]
        const float d[8] = {lo.x, lo.y, lo.z, lo.w, hi.x, hi.y, hi.z, hi.w};

        // ---- u-step: w = (Delta, 0); active c = 0..7; w[a]!=0 for r=0,1 ----
        {
            const float wb = dbr * maskLo;             // w[b]
            float t0 = fmaf(SIXTH, dh,  0.5f * s1[0]);
            float t1 = fmaf(SIXTH, dh4, 0.5f * s1[1]);
            float c0 = fmaf(wb, t0, s2[0]);
            float c1 = fmaf(wb, t1, s2[1]);
            float c2 = fmaf(wb, 0.5f * s1[2], s2[2]);
            float c3 = fmaf(wb, 0.5f * s1[3], s2[3]);
            #pragma unroll
            for (int c = 0; c < 8; ++c) {
                s3[0][c] = fmaf(c0, d[c], s3[0][c]);
                s3[1][c] = fmaf(c1, d[c], s3[1][c]);
                s3[2][c] = fmaf(c2, d[c], s3[2][c]);
                s3[3][c] = fmaf(c3, d[c], s3[3][c]);
            }
            s2[0] = fmaf(wb, fmaf(0.5f, dh,  s1[0]), s2[0]);
            s2[1] = fmaf(wb, fmaf(0.5f, dh4, s1[1]), s2[1]);
            s2[2] = fmaf(wb, s1[2], s2[2]);
            s2[3] = fmaf(wb, s1[3], s2[3]);
            s1[0] += dh;
            s1[1] += dh4;
        }
        // ---- v-step: w = (0, Delta); active c = 8..15; w[a]!=0 for r=2,3 ----
        {
            const float wb = dbr * maskHi;
            float t2 = fmaf(SIXTH, dh,  0.5f * s1[2]);
            float t3 = fmaf(SIXTH, dh4, 0.5f * s1[3]);
            float c0 = fmaf(wb, 0.5f * s1[0], s2[0]);
            float c1 = fmaf(wb, 0.5f * s1[1], s2[1]);
            float c2 = fmaf(wb, t2, s2[2]);
            float c3 = fmaf(wb, t3, s2[3]);
            #pragma unroll
            for (int c = 0; c < 8; ++c) {
                s3[0][8 + c] = fmaf(c0, d[c], s3[0][8 + c]);
                s3[1][8 + c] = fmaf(c1, d[c], s3[1][8 + c]);
                s3[2][8 + c] = fmaf(c2, d[c], s3[2][8 + c]);
                s3[3][8 + c] = fmaf(c3, d[c], s3[3][8 + c]);
            }
            s2[0] = fmaf(wb, s1[0], s2[0]);
            s2[1] = fmaf(wb, s1[1], s2[1]);
            s2[2] = fmaf(wb, fmaf(0.5f, dh,  s1[2]), s2[2]);
            s2[3] = fmaf(wb, fmaf(0.5f, dh4, s1[3]), s2[3]);
            s1[2] += dh;
            s1[3] += dh4;
        }
    }

    // ---- epilogue. Outputs concatenated: [SEQ,16][SEQ,256][SEQ,4096] ----
    const int o1 = i * 16;
    const int o2 = SEQ * 16 + i * 256;
    const long o3 = (long)SEQ * (16 + 256) + (long)i * 4096;

    // S2: lane-consecutive 4B stores, 256B contiguous per instr (nt: full
    // 64B sectors, keeps 8MB out of L2).
    #pragma unroll
    for (int r = 0; r < 4; ++r)
        __builtin_nontemporal_store(s2[r], out + o2 + L + 64 * r);
    // S1: 16 scattered 4B stores per position (512KB region total) - cached.
    if (b == 0) {
        #pragma unroll
        for (int r = 0; r < 4; ++r)
            out[o1 + h + 4 * r] = s1[r];
    }

    // S3: direct cached stores. Per r, lane L owns 64B contiguous at
    // o3 + r*1024 + L*16 (floats); 4 dwordx4 per lane, wave covers the 4KB
    // r-tile completely. L2 write-merge assembles full lines.
    #pragma unroll
    for (int r = 0; r < 4; ++r) {
        #pragma unroll
        for (int k = 0; k < 4; ++k) {
            f32x4 v = { s3[r][4 * k], s3[r][4 * k + 1],
                        s3[r][4 * k + 2], s3[r][4 * k + 3] };
            *(f32x4*)(out + o3 + r * 1024 + L * 16 + 4 * k) = v;
        }
    }
}

extern "C" void kernel_launch(void* const* d_in, const int* in_sizes, int n_in,
                              void* d_out, int out_size, void* d_ws, size_t ws_size,
                              hipStream_t stream) {
    (void)in_sizes; (void)n_in; (void)d_ws; (void)ws_size; (void)out_size;
    const float* x = (const float*)d_in[0];
    float* out = (float*)d_out;
    dim3 grid(SEQ / WAVES);
    dim3 block(WAVES * 64);
    hipLaunchKernelGGL(LeadLagSignature_48361331753748_kernel, grid, block, 0, stream,
                       x, out);
}

// Round 4
// 149.360 us; speedup vs baseline: 1.7256x; 1.1464x over previous
//
#include <hip/hip_runtime.h>
#include <stdint.h>

// LeadLagSignature: depth-3 signature of lead-lag path over sliding 16-patches.
// Increments alternate (Delta,0)/(0,Delta) -> half-sparse Chen updates.
// One wave per position; lane owns b=L&15, a in {h,h+4,h+8,h+12}, h=L>>4.
// Input: float32 [8192,8]. Output: float32, concat [8192,16][8192,256][8192,4096].
// R3: all __syncthreads removed (LDS buffers are wave-private; intra-wave DS
// ordering via s_waitcnt lgkmcnt(0) + sched_barrier). launch_bounds(256,2) so
// s3[4][16] lives in real VGPRs.
// R4: S3 goes back through the LDS transpose (stride-20 rows, conflict-free
// b128) so every global store is 1KB CONTIGUOUS, and is NON-TEMPORAL again:
// R3's direct strided 16B/64B cached stores caused 4x sector-request
// amplification + ~128MB read-for-ownership. nt + full-line stores stream
// straight out, no RFO. Barrier-free: write phase -> lgkmcnt(0) -> read
// phase -> lgkmcnt(0) (WAR before buffer reuse), wave-private.

#define SEQ   8192
#define IND   8
#define NM    15     // number of Delta rows per patch
#define WAVES 4

typedef float f32x4 __attribute__((ext_vector_type(4)));

__global__ __launch_bounds__(WAVES * 64, 2)
void LeadLagSignature_48361331753748_kernel(const float* __restrict__ x,
                                            float* __restrict__ out)
{
    __shared__ float dlds[WAVES][NM * 8];
    __shared__ float stage[WAVES][64 * 20];   // 5 KB per wave, wave-private
    const int tid = threadIdx.x;
    const int wv  = tid >> 6;
    const int L   = tid & 63;
    const int i   = blockIdx.x * WAVES + wv;   // output position
    const int h   = L >> 4;
    const int b   = L & 15;
    const int bm  = b & 7;
    const float maskLo = (b < 8) ? 1.0f : 0.0f;
    const float maskHi = 1.0f - maskLo;

    // Stage Deltas: Delta_m[c] = patch[m+1][c] - patch[m][c], patch[p] = xp[i+p]
    // (xp = 15 zero rows then x). 120 values; lanes cover idx and idx+64.
    // Wave-private buffer: no __syncthreads, only intra-wave DS ordering.
    float* dbuf = dlds[wv];
    #pragma unroll
    for (int q = 0; q < 2; ++q) {
        int idx = L + q * 64;
        if (idx < NM * 8) {
            int m = idx >> 3, c = idx & 7;
            int r1 = i + m - 14;   // row of patch[m+1]
            int r0 = i + m - 15;   // row of patch[m]
            float v1 = (r1 >= 0) ? x[r1 * IND + c] : 0.0f;
            float v0 = (r0 >= 0) ? x[r0 * IND + c] : 0.0f;
            dbuf[idx] = v1 - v0;
        }
    }
    asm volatile("s_waitcnt lgkmcnt(0)" ::: "memory");
    __builtin_amdgcn_sched_barrier(0);

    float s1[4] = {0.f, 0.f, 0.f, 0.f};       // S1[h+4r]
    float s2[4] = {0.f, 0.f, 0.f, 0.f};       // S2[h+4r, b]
    float s3[4][16];                          // S3[h+4r, b, :]
    #pragma unroll
    for (int r = 0; r < 4; ++r)
        #pragma unroll
        for (int c = 0; c < 16; ++c) s3[r][c] = 0.f;

    const float SIXTH = 0.16666666666666666f;

    for (int m = 0; m < NM; ++m) {
        const float* dm = dbuf + m * 8;
        const float4 lo = *(const float4*)(dm);      // broadcast, 16B aligned
        const float4 hi = *(const float4*)(dm + 4);
        const float dh  = dm[h];        // Delta[h]   = w[a] for rows h / h+8
        const float dh4 = dm[h + 4];    // Delta[h+4] = w[a] for rows h+4 / h+12
        const float dbr = dm[bm];       // Delta[b mod 8]
        const float d[8] = {lo.x, lo.y, lo.z, lo.w, hi.x, hi.y, hi.z, hi.w};

        // ---- u-step: w = (Delta, 0); active c = 0..7; w[a]!=0 for r=0,1 ----
        {
            const float wb = dbr * maskLo;             // w[b]
            float t0 = fmaf(SIXTH, dh,  0.5f * s1[0]);
            float t1 = fmaf(SIXTH, dh4, 0.5f * s1[1]);
            float c0 = fmaf(wb, t0, s2[0]);
            float c1 = fmaf(wb, t1, s2[1]);
            float c2 = fmaf(wb, 0.5f * s1[2], s2[2]);
            float c3 = fmaf(wb, 0.5f * s1[3], s2[3]);
            #pragma unroll
            for (int c = 0; c < 8; ++c) {
                s3[0][c] = fmaf(c0, d[c], s3[0][c]);
                s3[1][c] = fmaf(c1, d[c], s3[1][c]);
                s3[2][c] = fmaf(c2, d[c], s3[2][c]);
                s3[3][c] = fmaf(c3, d[c], s3[3][c]);
            }
            s2[0] = fmaf(wb, fmaf(0.5f, dh,  s1[0]), s2[0]);
            s2[1] = fmaf(wb, fmaf(0.5f, dh4, s1[1]), s2[1]);
            s2[2] = fmaf(wb, s1[2], s2[2]);
            s2[3] = fmaf(wb, s1[3], s2[3]);
            s1[0] += dh;
            s1[1] += dh4;
        }
        // ---- v-step: w = (0, Delta); active c = 8..15; w[a]!=0 for r=2,3 ----
        {
            const float wb = dbr * maskHi;
            float t2 = fmaf(SIXTH, dh,  0.5f * s1[2]);
            float t3 = fmaf(SIXTH, dh4, 0.5f * s1[3]);
            float c0 = fmaf(wb, 0.5f * s1[0], s2[0]);
            float c1 = fmaf(wb, 0.5f * s1[1], s2[1]);
            float c2 = fmaf(wb, t2, s2[2]);
            float c3 = fmaf(wb, t3, s2[3]);
            #pragma unroll
            for (int c = 0; c < 8; ++c) {
                s3[0][8 + c] = fmaf(c0, d[c], s3[0][8 + c]);
                s3[1][8 + c] = fmaf(c1, d[c], s3[1][8 + c]);
                s3[2][8 + c] = fmaf(c2, d[c], s3[2][8 + c]);
                s3[3][8 + c] = fmaf(c3, d[c], s3[3][8 + c]);
            }
            s2[0] = fmaf(wb, s1[0], s2[0]);
            s2[1] = fmaf(wb, s1[1], s2[1]);
            s2[2] = fmaf(wb, fmaf(0.5f, dh,  s1[2]), s2[2]);
            s2[3] = fmaf(wb, fmaf(0.5f, dh4, s1[3]), s2[3]);
            s1[2] += dh;
            s1[3] += dh4;
        }
    }

    // ---- epilogue. Outputs concatenated: [SEQ,16][SEQ,256][SEQ,4096] ----
    const int o1 = i * 16;
    const int o2 = SEQ * 16 + i * 256;
    const long o3 = (long)SEQ * (16 + 256) + (long)i * 4096;

    // S2: lane-consecutive 4B nt stores (256B contiguous per instr).
    #pragma unroll
    for (int r = 0; r < 4; ++r)
        __builtin_nontemporal_store(s2[r], out + o2 + L + 64 * r);
    // S1: 16 scattered 4B stores per position (512KB region total) - cached.
    if (b == 0) {
        #pragma unroll
        for (int r = 0; r < 4; ++r)
            out[o1 + h + 4 * r] = s1[r];
    }

    // S3: wave-private LDS transpose per r-tile -> contiguous 1KB nt stores.
    float* st = stage[wv];
    #pragma unroll
    for (int r = 0; r < 4; ++r) {
        // write phase: lane L's 16 floats at padded row L*20 (conflict-free b128)
        f32x4* wp = (f32x4*)(st + L * 20);
        wp[0] = (f32x4){ s3[r][0],  s3[r][1],  s3[r][2],  s3[r][3]  };
        wp[1] = (f32x4){ s3[r][4],  s3[r][5],  s3[r][6],  s3[r][7]  };
        wp[2] = (f32x4){ s3[r][8],  s3[r][9],  s3[r][10], s3[r][11] };
        wp[3] = (f32x4){ s3[r][12], s3[r][13], s3[r][14], s3[r][15] };
        asm volatile("s_waitcnt lgkmcnt(0)" ::: "memory");
        __builtin_amdgcn_sched_barrier(0);
        // read phase: lane L covers global floats tile + 256j + 4L (+0..3)
        #pragma unroll
        for (int j = 0; j < 4; ++j) {
            f32x4 v = *(const f32x4*)(st + (16 * j + (L >> 2)) * 20 + 4 * (L & 3));
            __builtin_nontemporal_store(v, (f32x4*)(out + o3 + 1024 * r + 256 * j + 4 * L));
        }
        asm volatile("s_waitcnt lgkmcnt(0)" ::: "memory");   // WAR: reads done
        __builtin_amdgcn_sched_barrier(0);                   // before reuse
    }
}

extern "C" void kernel_launch(void* const* d_in, const int* in_sizes, int n_in,
                              void* d_out, int out_size, void* d_ws, size_t ws_size,
                              hipStream_t stream) {
    (void)in_sizes; (void)n_in; (void)d_ws; (void)ws_size; (void)out_size;
    const float* x = (const float*)d_in[0];
    float* out = (float*)d_out;
    dim3 grid(SEQ / WAVES);
    dim3 block(WAVES * 64);
    hipLaunchKernelGGL(LeadLagSignature_48361331753748_kernel, grid, block, 0, stream,
                       x, out);
}

// Round 5
// 144.446 us; speedup vs baseline: 1.7843x; 1.0340x over previous
//
#include <hip/hip_runtime.h>
#include <stdint.h>

// LeadLagSignature: depth-3 signature of lead-lag path over sliding 16-patches.
// Increments alternate (Delta,0)/(0,Delta) -> half-sparse Chen updates.
// One wave per position; lane owns b=L&15, a in {h,h+4,h+8,h+12}, h=L>>4.
// Input: float32 [8192,8]. Output: float32, concat [8192,16][8192,256][8192,4096].
// R3: all __syncthreads removed (LDS buffers are wave-private; intra-wave DS
// ordering via s_waitcnt lgkmcnt(0) + sched_barrier). launch_bounds(256,2) so
// s3[4][16] lives in real VGPRs.
// R4: S3 through LDS transpose (stride-20 rows, conflict-free b128) so every
// global store is 1KB contiguous.
// R5 A/B probe: S3 stores CACHED instead of nt. Evidence: harness fill kernels
// write 572MB cached at 6.1 TB/s with FETCH~=0 -> full-line cached streaming
// writes incur no RFO and ride the memory-side L3; nt bypasses that path and
// appears to sustain only ~3.3 TB/s (kernel ~43us vs 23us write roofline).
// Single-variable change vs R4; revert if bench > ~155us.

#define SEQ   8192
#define IND   8
#define NM    15     // number of Delta rows per patch
#define WAVES 4

typedef float f32x4 __attribute__((ext_vector_type(4)));

__global__ __launch_bounds__(WAVES * 64, 2)
void LeadLagSignature_48361331753748_kernel(const float* __restrict__ x,
                                            float* __restrict__ out)
{
    __shared__ float dlds[WAVES][NM * 8];
    __shared__ float stage[WAVES][64 * 20];   // 5 KB per wave, wave-private
    const int tid = threadIdx.x;
    const int wv  = tid >> 6;
    const int L   = tid & 63;
    const int i   = blockIdx.x * WAVES + wv;   // output position
    const int h   = L >> 4;
    const int b   = L & 15;
    const int bm  = b & 7;
    const float maskLo = (b < 8) ? 1.0f : 0.0f;
    const float maskHi = 1.0f - maskLo;

    // Stage Deltas: Delta_m[c] = patch[m+1][c] - patch[m][c], patch[p] = xp[i+p]
    // (xp = 15 zero rows then x). 120 values; lanes cover idx and idx+64.
    // Wave-private buffer: no __syncthreads, only intra-wave DS ordering.
    float* dbuf = dlds[wv];
    #pragma unroll
    for (int q = 0; q < 2; ++q) {
        int idx = L + q * 64;
        if (idx < NM * 8) {
            int m = idx >> 3, c = idx & 7;
            int r1 = i + m - 14;   // row of patch[m+1]
            int r0 = i + m - 15;   // row of patch[m]
            float v1 = (r1 >= 0) ? x[r1 * IND + c] : 0.0f;
            float v0 = (r0 >= 0) ? x[r0 * IND + c] : 0.0f;
            dbuf[idx] = v1 - v0;
        }
    }
    asm volatile("s_waitcnt lgkmcnt(0)" ::: "memory");
    __builtin_amdgcn_sched_barrier(0);

    float s1[4] = {0.f, 0.f, 0.f, 0.f};       // S1[h+4r]
    float s2[4] = {0.f, 0.f, 0.f, 0.f};       // S2[h+4r, b]
    float s3[4][16];                          // S3[h+4r, b, :]
    #pragma unroll
    for (int r = 0; r < 4; ++r)
        #pragma unroll
        for (int c = 0; c < 16; ++c) s3[r][c] = 0.f;

    const float SIXTH = 0.16666666666666666f;

    for (int m = 0; m < NM; ++m) {
        const float* dm = dbuf + m * 8;
        const float4 lo = *(const float4*)(dm);      // broadcast, 16B aligned
        const float4 hi = *(const float4*)(dm + 4);
        const float dh  = dm[h];        // Delta[h]   = w[a] for rows h / h+8
        const float dh4 = dm[h + 4];    // Delta[h+4] = w[a] for rows h+4 / h+12
        const float dbr = dm[bm];       // Delta[b mod 8]
        const float d[8] = {lo.x, lo.y, lo.z, lo.w, hi.x, hi.y, hi.z, hi.w};

        // ---- u-step: w = (Delta, 0); active c = 0..7; w[a]!=0 for r=0,1 ----
        {
            const float wb = dbr * maskLo;             // w[b]
            float t0 = fmaf(SIXTH, dh,  0.5f * s1[0]);
            float t1 = fmaf(SIXTH, dh4, 0.5f * s1[1]);
            float c0 = fmaf(wb, t0, s2[0]);
            float c1 = fmaf(wb, t1, s2[1]);
            float c2 = fmaf(wb, 0.5f * s1[2], s2[2]);
            float c3 = fmaf(wb, 0.5f * s1[3], s2[3]);
            #pragma unroll
            for (int c = 0; c < 8; ++c) {
                s3[0][c] = fmaf(c0, d[c], s3[0][c]);
                s3[1][c] = fmaf(c1, d[c], s3[1][c]);
                s3[2][c] = fmaf(c2, d[c], s3[2][c]);
                s3[3][c] = fmaf(c3, d[c], s3[3][c]);
            }
            s2[0] = fmaf(wb, fmaf(0.5f, dh,  s1[0]), s2[0]);
            s2[1] = fmaf(wb, fmaf(0.5f, dh4, s1[1]), s2[1]);
            s2[2] = fmaf(wb, s1[2], s2[2]);
            s2[3] = fmaf(wb, s1[3], s2[3]);
            s1[0] += dh;
            s1[1] += dh4;
        }
        // ---- v-step: w = (0, Delta); active c = 8..15; w[a]!=0 for r=2,3 ----
        {
            const float wb = dbr * maskHi;
            float t2 = fmaf(SIXTH, dh,  0.5f * s1[2]);
            float t3 = fmaf(SIXTH, dh4, 0.5f * s1[3]);
            float c0 = fmaf(wb, 0.5f * s1[0], s2[0]);
            float c1 = fmaf(wb, 0.5f * s1[1], s2[1]);
            float c2 = fmaf(wb, t2, s2[2]);
            float c3 = fmaf(wb, t3, s2[3]);
            #pragma unroll
            for (int c = 0; c < 8; ++c) {
                s3[0][8 + c] = fmaf(c0, d[c], s3[0][8 + c]);
                s3[1][8 + c] = fmaf(c1, d[c], s3[1][8 + c]);
                s3[2][8 + c] = fmaf(c2, d[c], s3[2][8 + c]);
                s3[3][8 + c] = fmaf(c3, d[c], s3[3][8 + c]);
            }
            s2[0] = fmaf(wb, s1[0], s2[0]);
            s2[1] = fmaf(wb, s1[1], s2[1]);
            s2[2] = fmaf(wb, fmaf(0.5f, dh,  s1[2]), s2[2]);
            s2[3] = fmaf(wb, fmaf(0.5f, dh4, s1[3]), s2[3]);
            s1[2] += dh;
            s1[3] += dh4;
        }
    }

    // ---- epilogue. Outputs concatenated: [SEQ,16][SEQ,256][SEQ,4096] ----
    const int o1 = i * 16;
    const int o2 = SEQ * 16 + i * 256;
    const long o3 = (long)SEQ * (16 + 256) + (long)i * 4096;

    // S2: lane-consecutive 4B nt stores (256B contiguous per instr).
    #pragma unroll
    for (int r = 0; r < 4; ++r)
        __builtin_nontemporal_store(s2[r], out + o2 + L + 64 * r);
    // S1: 16 scattered 4B stores per position (512KB region total) - cached.
    if (b == 0) {
        #pragma unroll
        for (int r = 0; r < 4; ++r)
            out[o1 + h + 4 * r] = s1[r];
    }

    // S3: wave-private LDS transpose per r-tile -> contiguous 1KB CACHED stores
    // (full-line coverage; rides L2/L3 write path like the 6.1 TB/s fill).
    float* st = stage[wv];
    #pragma unroll
    for (int r = 0; r < 4; ++r) {
        // write phase: lane L's 16 floats at padded row L*20 (conflict-free b128)
        f32x4* wp = (f32x4*)(st + L * 20);
        wp[0] = (f32x4){ s3[r][0],  s3[r][1],  s3[r][2],  s3[r][3]  };
        wp[1] = (f32x4){ s3[r][4],  s3[r][5],  s3[r][6],  s3[r][7]  };
        wp[2] = (f32x4){ s3[r][8],  s3[r][9],  s3[r][10], s3[r][11] };
        wp[3] = (f32x4){ s3[r][12], s3[r][13], s3[r][14], s3[r][15] };
        asm volatile("s_waitcnt lgkmcnt(0)" ::: "memory");
        __builtin_amdgcn_sched_barrier(0);
        // read phase: lane L covers global floats tile + 256j + 4L (+0..3)
        #pragma unroll
        for (int j = 0; j < 4; ++j) {
            f32x4 v = *(const f32x4*)(st + (16 * j + (L >> 2)) * 20 + 4 * (L & 3));
            *(f32x4*)(out + o3 + 1024 * r + 256 * j + 4 * L) = v;
        }
        asm volatile("s_waitcnt lgkmcnt(0)" ::: "memory");   // WAR: reads done
        __builtin_amdgcn_sched_barrier(0);                   // before reuse
    }
}

extern "C" void kernel_launch(void* const* d_in, const int* in_sizes, int n_in,
                              void* d_out, int out_size, void* d_ws, size_t ws_size,
                              hipStream_t stream) {
    (void)in_sizes; (void)n_in; (void)d_ws; (void)ws_size; (void)out_size;
    const float* x = (const float*)d_in[0];
    float* out = (float*)d_out;
    dim3 grid(SEQ / WAVES);
    dim3 block(WAVES * 64);
    hipLaunchKernelGGL(LeadLagSignature_48361331753748_kernel, grid, block, 0, stream,
                       x, out);
}